// Round 18
// baseline (298.412 us; speedup 1.0000x reference)
//
#include <hip/hip_runtime.h>
#include <stdint.h>

typedef unsigned short u16;
typedef __attribute__((ext_vector_type(4))) float f32x4;
typedef __attribute__((ext_vector_type(16))) float f32x16;
typedef __attribute__((ext_vector_type(8))) __bf16 bf16x8;
typedef __attribute__((ext_vector_type(4))) u16 u16x4;
typedef __attribute__((ext_vector_type(8))) u16 u16x8;
typedef __attribute__((ext_vector_type(4))) unsigned int u32x4;

#define S_LEN 2048
#define HIDDEN 4096
#define NHEAD 32
#define NKVH 8
#define HD 128
#define WIN 1024

__device__ __forceinline__ float bf2f(u16 u) {
  union { unsigned int i; float f; } x; x.i = ((unsigned int)u) << 16; return x.f;
}
__device__ __forceinline__ u16 f2bf(float f) {
  union { float f; unsigned int i; } x; x.f = f;
  unsigned int r = x.i + 0x7FFFu + ((x.i >> 16) & 1u);
  return (u16)(r >> 16);
}

__device__ __forceinline__ void gload16(const void* g, void* l) {
  __builtin_amdgcn_global_load_lds((const __attribute__((address_space(1))) void*)g,
                                   (__attribute__((address_space(3))) void*)l, 16, 0, 0);
}

__device__ __forceinline__ unsigned int cvtpk_bf16(float a, float b) {
  unsigned int w;
  asm("v_cvt_pk_bf16_f32 %0, %1, %2" : "=v"(w) : "v"(a), "v"(b));
  return w;
}

// ---------------- fused fp32->bf16 transpose tile (device fn, shared smem) ----------------
__device__ __forceinline__ void transp_f32(const float* __restrict__ in, int istride,
                                           u16* __restrict__ out, int ostride,
                                           int bx, int by, char* smem) {
  float (*tile)[68] = (float (*)[68])smem;  // 64x68 f32 = 17408 B
  int r0 = bx * 64, c0 = by * 64;
  int t = threadIdx.x;
  int tr = t >> 4;
  int tc = (t & 15) * 4;
#pragma unroll
  for (int i = 0; i < 4; ++i) {
    int r = i * 16 + tr;
    *(f32x4*)&tile[r][tc] = *(const f32x4*)(in + (size_t)(r0 + r) * istride + c0 + tc);
  }
  __syncthreads();
#pragma unroll
  for (int i = 0; i < 4; ++i) {
    int rr = i * 16 + tr;
    u16x4 o;
#pragma unroll
    for (int j = 0; j < 4; ++j) o[j] = f2bf(tile[tc + j][rr]);
    *(u16x4*)(out + (size_t)(c0 + rr) * ostride + r0 + tc) = o;
  }
}

// ---------------- prep: X conv + Wq/Wk/Wv transpose + bias concat (+ optional Wo^T) ----------------
// blocks [0,4096): conv X; [4096,8192): Wq^T; [8192,9216): Wk^T; [9216,10240): Wv^T;
// [10240,10264): bias; [10264,14360): Wo^T -> WoT2 (only launched when workspace allows).
__global__ __launch_bounds__(256) void prep_k(const float* __restrict__ X,
                                              const float* __restrict__ Wq, const float* __restrict__ Wk,
                                              const float* __restrict__ Wv, const float* __restrict__ Wo,
                                              const float* __restrict__ bq, const float* __restrict__ bk,
                                              const float* __restrict__ bv,
                                              u16* __restrict__ Xb, u16* __restrict__ WT,
                                              u16* __restrict__ WoT2, float* __restrict__ bqkv) {
  __shared__ __align__(16) char smem[17408];
  int bid = blockIdx.x;
  if (bid < 4096) {
    size_t i = ((size_t)bid * 256 + threadIdx.x) * 8;
    f32x4 a = *(const f32x4*)(X + i);
    f32x4 b = *(const f32x4*)(X + i + 4);
    u16x8 o;
    o[0] = f2bf(a[0]); o[1] = f2bf(a[1]); o[2] = f2bf(a[2]); o[3] = f2bf(a[3]);
    o[4] = f2bf(b[0]); o[5] = f2bf(b[1]); o[6] = f2bf(b[2]); o[7] = f2bf(b[3]);
    *(u16x8*)(Xb + i) = o;
  } else if (bid < 8192) {
    int tt = bid - 4096;
    transp_f32(Wq, 4096, WT, 4096, tt & 63, tt >> 6, smem);
  } else if (bid < 9216) {
    int tt = bid - 8192;
    transp_f32(Wk, 1024, WT + (size_t)4096 * 4096, 4096, tt & 63, tt >> 6, smem);
  } else if (bid < 10240) {
    int tt = bid - 9216;
    transp_f32(Wv, 1024, WT + (size_t)5120 * 4096, 4096, tt & 63, tt >> 6, smem);
  } else if (bid < 10264) {
    int i = (bid - 10240) * 256 + threadIdx.x;
    float v = (i < 4096) ? bq[i] : (i < 5120 ? bk[i - 4096] : bv[i - 5120]);
    bqkv[i] = v;
  } else {
    int tt = bid - 10264;
    transp_f32(Wo, 4096, WoT2, 4096, tt & 63, tt >> 6, smem);
  }
}

// ---------------- QKV GEMM: 128x384 tile, 256 WGs (100% CU), fused RoPE/scatter epilogue ----------------
__global__ __launch_bounds__(512, 2) void gemmqkv_k(const u16* __restrict__ A, const u16* __restrict__ Bt,
                                                    const float* __restrict__ bias,
                                                    const int* __restrict__ pos,
                                                    const float* __restrict__ cosT, const float* __restrict__ sinT,
                                                    u16* __restrict__ Q, u16* __restrict__ Kf,
                                                    u16* __restrict__ Vf, int K) {
  __shared__ __align__(16) u16 SM[49152];  // SA: 3x4096 u16, SB: 3x12288 u16 (96KB); epilogue reuses
  u16* SA = SM;
  u16* SB = SM + 12288;

  int tid = threadIdx.x;
  int w = tid >> 6, l = tid & 63;
  int cl = l & 15, g = l >> 4;
  int wr = w >> 2, wc = w & 3;

  int cpx = gridDim.x >> 3;  // XCD-bijective swizzle (256 % 8 == 0)
  int wg = (blockIdx.x & 7) * cpx + (blockIdx.x >> 3);
  int bm = wg & 15, bn = wg >> 4;  // nbm = 16, bn in [0,16)

  const u16* Ag = A + (size_t)(bm * 128) * K;
  const u16* Bg = Bt + (size_t)(bn * 384) * K;
  int srow = w * 16 + (l >> 2);                  // staging row within a 128-row unit
  int csrc = ((l & 3) ^ ((l >> 3) & 3)) * 8;     // inverse-swizzled global k-chunk
  int rdc = (g ^ ((cl >> 1) & 3)) << 3;          // forward swizzle on fragment ds_read

  f32x4 acc[4][6] = {};
  int NT = K >> 5;

  auto stage = [&](int slot, int tt, int u) {
    if (u == 0) {
      gload16(Ag + (size_t)srow * K + tt * 32 + csrc,
              (void*)(SA + slot * 4096 + w * 512));
    } else {
      int ub = u - 1;
      gload16(Bg + (size_t)(ub * 128 + srow) * K + tt * 32 + csrc,
              (void*)(SB + slot * 12288 + ub * 4096 + w * 512));
    }
  };

#pragma unroll
  for (int u = 0; u < 4; ++u) stage(0, 0, u);
#pragma unroll
  for (int u = 0; u < 4; ++u) stage(1, 1, u);

  for (int t = 0; t < NT; ++t) {
    asm volatile("s_waitcnt vmcnt(4)" ::: "memory");  // tile t done; t+1's 4 stay in flight
    __builtin_amdgcn_s_barrier();
    asm volatile("" ::: "memory");

    int slot = t % 3, ss = (t + 2) % 3;
    int ts = t + 2; if (ts >= NT) ts -= NT;  // dummy wrap keeps vmcnt accounting uniform
#pragma unroll
    for (int u = 0; u < 4; ++u) stage(ss, ts, u);

    const u16* sa = SA + slot * 4096;
    const u16* sb = SB + slot * 12288;
    bf16x8 af[4], bf[6];
#pragma unroll
    for (int mi = 0; mi < 4; ++mi)
      af[mi] = *(const bf16x8*)(sa + (wr * 64 + mi * 16 + cl) * 32 + rdc);
#pragma unroll
    for (int ni = 0; ni < 6; ++ni)
      bf[ni] = *(const bf16x8*)(sb + (wc * 96 + ni * 16 + cl) * 32 + rdc);
    __builtin_amdgcn_s_setprio(1);
#pragma unroll
    for (int mi = 0; mi < 4; ++mi)
#pragma unroll
      for (int ni = 0; ni < 6; ++ni)
        acc[mi][ni] = __builtin_amdgcn_mfma_f32_16x16x32_bf16(af[mi], bf[ni], acc[mi][ni], 0, 0, 0);
    __builtin_amdgcn_s_setprio(0);
  }

  asm volatile("s_waitcnt vmcnt(0)" ::: "memory");  // drain trailing dummy stages
  __syncthreads();

  // ---- epilogue: 2 passes of 64 rows via LDS tile [64][392] (stride 784B = 49*16B) ----
  u16 (*tileL)[392] = (u16 (*)[392])SM;
  const float qs = 0.08838834764831845f;  // 1/sqrt(128)
#pragma unroll
  for (int hp = 0; hp < 2; ++hp) {
    if (wr == hp) {
#pragma unroll
      for (int mi = 0; mi < 4; ++mi)
#pragma unroll
        for (int ni = 0; ni < 6; ++ni) {
          int col = wc * 96 + ni * 16 + cl;
          float bb = bias[bn * 384 + col];
#pragma unroll
          for (int r = 0; r < 4; ++r)
            tileL[mi * 16 + g * 4 + r][col] = f2bf(acc[mi][ni][r] + bb);
        }
    }
    __syncthreads();

    int s0 = bm * 128 + hp * 64;
#pragma unroll
    for (int hl = 0; hl < 3; ++hl) {
      int c0 = bn * 384 + hl * 128;  // 128-aligned global col base
      int hidx = c0 >> 7;            // [0,48): <32 Q, <40 K, else V
      if (hidx < 32) {
        int r = tid >> 3, u = tid & 7;
        int s = s0 + r;
        int ps = pos[s];
        const float* cb = cosT + (size_t)ps * 128;
        const float* sb = sinT + (size_t)ps * 128;
        u16* dst = Q + ((size_t)hidx * S_LEN + s) * HD;
        int d0 = u * 8;
        u16x8 xlo = *(const u16x8*)&tileL[r][hl * 128 + d0];
        u16x8 xhi = *(const u16x8*)&tileL[r][hl * 128 + d0 + 64];
        u16x8 lo, hi;
#pragma unroll
        for (int j = 0; j < 8; ++j) {
          int d = d0 + j;
          float x0 = bf2f(xlo[j]);
          float x1 = bf2f(xhi[j]);
          lo[j] = f2bf((x0 * cb[d] - x1 * sb[d]) * qs);
          hi[j] = f2bf((x1 * cb[d + 64] + x0 * sb[d + 64]) * qs);
        }
        *(u16x8*)(dst + d0) = lo;
        *(u16x8*)(dst + d0 + 64) = hi;
      } else if (hidx < 40) {
        int kh = hidx - 32;
        int r = tid >> 3, u = tid & 7;
        int s = s0 + r;
        int ps = pos[s];
        const float* cb = cosT + (size_t)ps * 128;
        const float* sb = sinT + (size_t)ps * 128;
        int t2 = s >> 5, cr = s & 31;
        int d0 = u * 8;
        u16x8 xlo = *(const u16x8*)&tileL[r][hl * 128 + d0];
        u16x8 xhi = *(const u16x8*)&tileL[r][hl * 128 + d0 + 64];
        u16x8 lo, hi;
#pragma unroll
        for (int j = 0; j < 8; ++j) {
          int d = d0 + j;
          float x0 = bf2f(xlo[j]);
          float x1 = bf2f(xhi[j]);
          lo[j] = f2bf(x0 * cb[d] - x1 * sb[d]);
          hi[j] = f2bf(x1 * cb[d + 64] + x0 * sb[d + 64]);
        }
        size_t base_lo = ((size_t)(kh * 64 + t2) * 8 + (d0 >> 4)) * 512 + (size_t)(cr + 32 * ((d0 >> 3) & 1)) * 8;
        *(u16x8*)(Kf + base_lo) = lo;
        int dh = d0 + 64;
        size_t base_hi = ((size_t)(kh * 64 + t2) * 8 + (dh >> 4)) * 512 + (size_t)(cr + 32 * ((dh >> 3) & 1)) * 8;
        *(u16x8*)(Kf + base_hi) = hi;
      } else {
        int kh = hidx - 40;
#pragma unroll
        for (int i = 0; i < 2; ++i) {
          int c = i * 512 + tid;
          int lv = c & 63, sl = (c >> 6) & 1, dt = (c >> 7) & 3, t_local = (c >> 9) & 1;
          int rl = t_local * 32 + sl * 16 + (lv >> 5) * 8;
          int colv = hl * 128 + dt * 32 + (lv & 31);
          u16x8 o;
#pragma unroll
          for (int j = 0; j < 8; ++j) o[j] = tileL[rl + j][colv];
          int tglob = bm * 4 + hp * 2 + t_local;
          size_t addr = ((size_t)(kh * 512 + tglob * 8 + dt * 2 + sl)) * 512 + (size_t)lv * 8;
          *(u16x8*)(Vf + addr) = o;
        }
      }
    }
    __syncthreads();
  }
}

// ---------------- Pipelined GEMM v4 (out-proj): r9-verified structure ----------------
template <int BM, int BN, int MINW, typename TOUT>
__global__ __launch_bounds__(256, MINW) void gemm4_k(const u16* __restrict__ A, const u16* __restrict__ Bt,
                                                     const float* __restrict__ bias, TOUT* __restrict__ C,
                                                     int M, int N, int K) {
  constexpr int WM = BM / 2, WN = BN / 2;
  constexpr int MRA = WM / 16, MRB = WN / 16;
  constexpr int NA = BM / 64, NB = BN / 64;
  constexpr int NL = NA + NB;
  __shared__ __align__(16) u16 SA[3 * BM * 32];
  __shared__ __align__(16) u16 SB[3 * BN * 32];

  int tid = threadIdx.x;
  int w = tid >> 6, l = tid & 63;
  int cl = l & 15, g = l >> 4;
  int wr = w >> 1, wc = w & 1;

  int cpx = gridDim.x >> 3;
  int wg = (blockIdx.x & 7) * cpx + (blockIdx.x >> 3);
  int nbm = M / BM;
  int bm = wg % nbm, bn = wg / nbm;

  const u16* Ag = A + (size_t)(bm * BM) * K;
  const u16* Bg = Bt + (size_t)(bn * BN) * K;
  int srow = w * 16 + (l >> 2);
  int csrc = ((l & 3) ^ ((l >> 3) & 3)) * 8;
  int rdc = (g ^ ((cl >> 1) & 3)) << 3;

  f32x4 acc[MRA][MRB] = {};
  int NT = K >> 5;

  auto stage = [&](int slot, int tt, int h) {
    if (h < NA) {
      gload16(Ag + (size_t)(h * 64 + srow) * K + tt * 32 + csrc,
              (void*)(SA + slot * (BM * 32) + (h * 64 + w * 16) * 32));
    } else {
      int hb = h - NA;
      gload16(Bg + (size_t)(hb * 64 + srow) * K + tt * 32 + csrc,
              (void*)(SB + slot * (BN * 32) + (hb * 64 + w * 16) * 32));
    }
  };

#pragma unroll
  for (int h = 0; h < NL; ++h) stage(0, 0, h);
#pragma unroll
  for (int h = 0; h < NL; ++h) stage(1, 1, h);

  for (int t = 0; t < NT; ++t) {
    if constexpr (NL == 5) asm volatile("s_waitcnt vmcnt(5)" ::: "memory");
    else if constexpr (NL == 4) asm volatile("s_waitcnt vmcnt(4)" ::: "memory");
    else asm volatile("s_waitcnt vmcnt(3)" ::: "memory");
    __builtin_amdgcn_s_barrier();
    asm volatile("" ::: "memory");

    int slot = t % 3, ss = (t + 2) % 3;
    int ts = t + 2; if (ts >= NT) ts -= NT;
#pragma unroll
    for (int h = 0; h < NL; ++h) stage(ss, ts, h);

    const u16* sa = SA + slot * (BM * 32);
    const u16* sb = SB + slot * (BN * 32);
    bf16x8 af[MRA], bf[MRB];
#pragma unroll
    for (int mi = 0; mi < MRA; ++mi)
      af[mi] = *(const bf16x8*)(sa + (wr * WM + mi * 16 + cl) * 32 + rdc);
#pragma unroll
    for (int ni = 0; ni < MRB; ++ni)
      bf[ni] = *(const bf16x8*)(sb + (wc * WN + ni * 16 + cl) * 32 + rdc);
    __builtin_amdgcn_s_setprio(1);
#pragma unroll
    for (int mi = 0; mi < MRA; ++mi)
#pragma unroll
      for (int ni = 0; ni < MRB; ++ni)
        acc[mi][ni] = __builtin_amdgcn_mfma_f32_16x16x32_bf16(af[mi], bf[ni], acc[mi][ni], 0, 0, 0);
    __builtin_amdgcn_s_setprio(0);
  }

  asm volatile("s_waitcnt vmcnt(0)" ::: "memory");

#pragma unroll
  for (int mi = 0; mi < MRA; ++mi) {
    int row0 = bm * BM + wr * WM + mi * 16 + g * 4;
#pragma unroll
    for (int ni = 0; ni < MRB; ++ni) {
      int col = bn * BN + wc * WN + ni * 16 + cl;
      float bb = bias[col];
      f32x4 a = acc[mi][ni];
#pragma unroll
      for (int r = 0; r < 4; ++r) {
        float v = a[r] + bb;
        if constexpr (sizeof(TOUT) == 2) C[(size_t)(row0 + r) * N + col] = f2bf(v);
        else C[(size_t)(row0 + r) * N + col] = v;
      }
    }
  }
}

// ---------------- flash attention (r11-best) + optional Wo^T piggyback (fallback only) ----------------
// blocks [0,512): attn; blocks [512, 512+nwot): Wo^T transpose (nwot=0 when prep handles Wo^T).
__global__ __launch_bounds__(256, 2) void attnwot_k(const u16* __restrict__ Q, const u16* __restrict__ Kf,
                                                    const u16* __restrict__ Vf, u16* __restrict__ O,
                                                    const float* __restrict__ Wo, u16* __restrict__ WT) {
  __shared__ __align__(16) char smem[17408];
  if (blockIdx.x >= 512) {
    int tt = blockIdx.x - 512;
    transp_f32(Wo, 4096, WT, 4096, tt & 63, tt >> 6, smem);
    return;
  }
  int l = threadIdx.x & 63, w = threadIdx.x >> 6;
  int col = l & 31, hi = l >> 5;
  int bid = blockIdx.x;
  int kh = bid & 7;
  int head = (bid >> 3) & 3;
  int qbp = bid >> 5;
  int qb = (qbp & 1) ? (15 - (qbp >> 1)) : (qbp >> 1);
  int h = kh * 4 + head;
  int q0 = qb * 128 + w * 32;

  bf16x8 qf[8];
  const u16* qbase = Q + ((size_t)h * S_LEN + q0 + col) * HD + hi * 8;
#pragma unroll
  for (int ks = 0; ks < 8; ++ks) qf[ks] = *(const bf16x8*)(qbase + ks * 16);

  f32x16 ot[4];
#pragma unroll
  for (int dt = 0; dt < 4; ++dt)
#pragma unroll
    for (int r = 0; r < 16; ++r) ot[dt][r] = 0.f;
  float m_r = -3.0e38f, l_r = 0.f;

  const u16* kf0 = Kf + (size_t)kh * 64 * 4096 + (size_t)l * 8;
  const u16* vf0 = Vf + (size_t)kh * 512 * 512 + (size_t)l * 8;

  int jstart = q0 >= WIN ? q0 - WIN : 0;
  bf16x8 kfr[8];
  {
    const u16* kb = kf0 + (size_t)(jstart >> 5) * 4096;
#pragma unroll
    for (int ks = 0; ks < 8; ++ks) kfr[ks] = *(const bf16x8*)(kb + ks * 512);
  }

  for (int j0 = jstart; j0 <= q0; j0 += 32) {
    int t = j0 >> 5;
    f32x16 sA = {}, sB = {};
#pragma unroll
    for (int ks = 0; ks < 4; ++ks)
      sA = __builtin_amdgcn_mfma_f32_32x32x16_bf16(kfr[ks], qf[ks], sA, 0, 0, 0);
#pragma unroll
    for (int ks = 4; ks < 8; ++ks)
      sB = __builtin_amdgcn_mfma_f32_32x32x16_bf16(kfr[ks], qf[ks], sB, 0, 0, 0);
    int tn = (j0 + 32 <= q0) ? (t + 1) : t;
    const u16* kbn = kf0 + (size_t)tn * 4096;
    bf16x8 kfn[8];
#pragma unroll
    for (int ks = 0; ks < 8; ++ks) kfn[ks] = *(const bf16x8*)(kbn + ks * 512);
    const u16* vb = vf0 + (size_t)t * 4096;
    bf16x8 vfr[8];
#pragma unroll
    for (int c = 0; c < 8; ++c) vfr[c] = *(const bf16x8*)(vb + c * 512);

    f32x16 s = sA + sB;

    if (j0 + 31 > q0 || j0 < q0 - 992) {
      int q = q0 + col;
#pragma unroll
      for (int r = 0; r < 16; ++r) {
        int kv = j0 + (r & 3) + 8 * (r >> 2) + 4 * hi;
        if (kv > q || kv <= q - WIN) s[r] = -3.0e38f;
      }
    }
    float vm = fmaxf(fmaxf(fmaxf(s[0], s[1]), fmaxf(s[2], s[3])),
                     fmaxf(fmaxf(s[4], s[5]), fmaxf(s[6], s[7])));
    vm = fmaxf(vm, fmaxf(fmaxf(fmaxf(s[8], s[9]), fmaxf(s[10], s[11])),
                         fmaxf(fmaxf(s[12], s[13]), fmaxf(s[14], s[15]))));
    vm = fmaxf(vm, __shfl_xor(vm, 32));
    float mnew = fmaxf(m_r, vm);
    float sc = __expf(m_r - mnew);
    m_r = mnew;
    float rs = 0.f;
#pragma unroll
    for (int r = 0; r < 16; ++r) {
      float pv = __expf(s[r] - mnew);
      s[r] = pv;
      rs += pv;
    }
    rs += __shfl_xor(rs, 32);
    l_r = l_r * sc + rs;
#pragma unroll
    for (int dt = 0; dt < 4; ++dt)
#pragma unroll
      for (int r = 0; r < 16; ++r) ot[dt][r] *= sc;

    bf16x8 pb[2];
#pragma unroll
    for (int sl = 0; sl < 2; ++sl) {
      int b = sl * 8;
      unsigned int a0 = cvtpk_bf16(s[b + 0], s[b + 1]);
      unsigned int c0 = cvtpk_bf16(s[b + 4], s[b + 5]);
      asm("v_permlane32_swap_b32 %0, %1" : "+v"(a0), "+v"(c0));
      unsigned int a1 = cvtpk_bf16(s[b + 2], s[b + 3]);
      unsigned int c1 = cvtpk_bf16(s[b + 6], s[b + 7]);
      asm("v_permlane32_swap_b32 %0, %1" : "+v"(a1), "+v"(c1));
      u32x4 pv = {a0, a1, c0, c1};
      pb[sl] = __builtin_bit_cast(bf16x8, pv);
    }
#pragma unroll
    for (int dt = 0; dt < 4; ++dt) {
      ot[dt] = __builtin_amdgcn_mfma_f32_32x32x16_bf16(vfr[dt * 2 + 0], pb[0], ot[dt], 0, 0, 0);
      ot[dt] = __builtin_amdgcn_mfma_f32_32x32x16_bf16(vfr[dt * 2 + 1], pb[1], ot[dt], 0, 0, 0);
    }
#pragma unroll
    for (int ks = 0; ks < 8; ++ks) kfr[ks] = kfn[ks];
  }

  float inv = 1.0f / l_r;
#pragma unroll
  for (int dt = 0; dt < 4; ++dt) {
#pragma unroll
    for (int g2 = 0; g2 < 4; ++g2) {
      u16x4 o;
#pragma unroll
      for (int i = 0; i < 4; ++i) o[i] = f2bf(ot[dt][g2 * 4 + i] * inv);
      *(u16x4*)(O + (size_t)(q0 + col) * HIDDEN + h * HD + dt * 32 + g2 * 8 + hi * 4) = o;
    }
  }
}

extern "C" void kernel_launch(void* const* d_in, const int* in_sizes, int n_in,
                              void* d_out, int out_size, void* d_ws, size_t ws_size,
                              hipStream_t stream) {
  const float* X = (const float*)d_in[0];
  const int* pos = (const int*)d_in[2];
  const float* cosT = (const float*)d_in[3];
  const float* sinT = (const float*)d_in[4];
  const float* Wq = (const float*)d_in[5];
  const float* bq = (const float*)d_in[6];
  const float* Wk = (const float*)d_in[7];
  const float* bk = (const float*)d_in[8];
  const float* Wv = (const float*)d_in[9];
  const float* bv = (const float*)d_in[10];
  const float* Wo = (const float*)d_in[11];
  const float* bo = (const float*)d_in[12];
  float* out = (float*)d_out;

  const size_t MB = 1ull << 20;
  char* ws = (char*)d_ws;
  u16* WT = (u16*)ws;                     // 48MB: Wqkv^T bf16 (Wo^T overwrites here in fallback)
  u16* Xb = (u16*)(ws + 48 * MB);         // 16MB: X bf16 (dead after QKV GEMM); attnO reuses
  u16* attnO = Xb;
  u16* Qs = (u16*)(ws + 64 * MB);         // 16MB: Q [32][2048][128]
  u16* Kfr = (u16*)(ws + 88 * MB);        // 4MB: K fragment-packed
  u16* Vfr = (u16*)(ws + 92 * MB);        // 4MB: V fragment-packed
  float* bqkv = (float*)(ws + 96 * MB);   // 24KB
  u16* WoT2 = (u16*)(ws + 97 * MB);       // 32MB: Wo^T (separate region, main path only)

  // Main path needs ws_size >= 97MB + 32MB. Deterministic branch (ws_size fixed per problem).
  bool sepWo = (ws_size >= 130 * MB);

  if (sepWo) {
    // prep: conv + Wq/Wk/Wv^T + bias + Wo^T (streamed at full BW, away from attn)
    prep_k<<<14360, 256, 0, stream>>>(X, Wq, Wk, Wv, Wo, bq, bk, bv, Xb, WT, WoT2, bqkv);
    gemmqkv_k<<<256, 512, 0, stream>>>(Xb, WT, bqkv, pos, cosT, sinT, Qs, Kfr, Vfr, 4096);
    // attn pure: K/V stay L2-resident per XCD (kh == XCD), no Wo streaming interference
    attnwot_k<<<512, 256, 0, stream>>>(Qs, Kfr, Vfr, attnO, Wo, WoT2);
    gemm4_k<128, 128, 3, float><<<512, 256, 0, stream>>>(attnO, WoT2, bo, out, 2048, 4096, 4096);
  } else {
    // fallback: exact r17 configuration
    prep_k<<<10264, 256, 0, stream>>>(X, Wq, Wk, Wv, Wo, bq, bk, bv, Xb, WT, WoT2, bqkv);
    gemmqkv_k<<<256, 512, 0, stream>>>(Xb, WT, bqkv, pos, cosT, sinT, Qs, Kfr, Vfr, 4096);
    attnwot_k<<<4608, 256, 0, stream>>>(Qs, Kfr, Vfr, attnO, Wo, WT);
    gemm4_k<128, 128, 3, float><<<512, 256, 0, stream>>>(attnO, WT, bo, out, 2048, 4096, 4096);
  }
}

// Round 19
// 287.853 us; speedup vs baseline: 1.0367x; 1.0367x over previous
//
#include <hip/hip_runtime.h>
#include <stdint.h>

typedef unsigned short u16;
typedef __attribute__((ext_vector_type(4))) float f32x4;
typedef __attribute__((ext_vector_type(16))) float f32x16;
typedef __attribute__((ext_vector_type(8))) __bf16 bf16x8;
typedef __attribute__((ext_vector_type(4))) u16 u16x4;
typedef __attribute__((ext_vector_type(8))) u16 u16x8;
typedef __attribute__((ext_vector_type(4))) unsigned int u32x4;

#define S_LEN 2048
#define HIDDEN 4096
#define NHEAD 32
#define NKVH 8
#define HD 128
#define WIN 1024

__device__ __forceinline__ float bf2f(u16 u) {
  union { unsigned int i; float f; } x; x.i = ((unsigned int)u) << 16; return x.f;
}
__device__ __forceinline__ u16 f2bf(float f) {
  union { float f; unsigned int i; } x; x.f = f;
  unsigned int r = x.i + 0x7FFFu + ((x.i >> 16) & 1u);
  return (u16)(r >> 16);
}

__device__ __forceinline__ void gload16(const void* g, void* l) {
  __builtin_amdgcn_global_load_lds((const __attribute__((address_space(1))) void*)g,
                                   (__attribute__((address_space(3))) void*)l, 16, 0, 0);
}

__device__ __forceinline__ unsigned int cvtpk_bf16(float a, float b) {
  unsigned int w;
  asm("v_cvt_pk_bf16_f32 %0, %1, %2" : "=v"(w) : "v"(a), "v"(b));
  return w;
}

// ---------------- fused fp32->bf16 transpose tile (device fn, shared smem) ----------------
__device__ __forceinline__ void transp_f32(const float* __restrict__ in, int istride,
                                           u16* __restrict__ out, int ostride,
                                           int bx, int by, char* smem) {
  float (*tile)[68] = (float (*)[68])smem;  // 64x68 f32 = 17408 B
  int r0 = bx * 64, c0 = by * 64;
  int t = threadIdx.x;
  int tr = t >> 4;
  int tc = (t & 15) * 4;
#pragma unroll
  for (int i = 0; i < 4; ++i) {
    int r = i * 16 + tr;
    *(f32x4*)&tile[r][tc] = *(const f32x4*)(in + (size_t)(r0 + r) * istride + c0 + tc);
  }
  __syncthreads();
#pragma unroll
  for (int i = 0; i < 4; ++i) {
    int rr = i * 16 + tr;
    u16x4 o;
#pragma unroll
    for (int j = 0; j < 4; ++j) o[j] = f2bf(tile[tc + j][rr]);
    *(u16x4*)(out + (size_t)(c0 + rr) * ostride + r0 + tc) = o;
  }
}

// ---------------- prep: X conv + Wq/Wk/Wv transpose + bias concat (1 launch) ----------------
__global__ __launch_bounds__(256) void prep_k(const float* __restrict__ X,
                                              const float* __restrict__ Wq, const float* __restrict__ Wk,
                                              const float* __restrict__ Wv,
                                              const float* __restrict__ bq, const float* __restrict__ bk,
                                              const float* __restrict__ bv,
                                              u16* __restrict__ Xb, u16* __restrict__ WT,
                                              float* __restrict__ bqkv) {
  __shared__ __align__(16) char smem[17408];
  int bid = blockIdx.x;
  if (bid < 4096) {
    size_t i = ((size_t)bid * 256 + threadIdx.x) * 8;
    f32x4 a = *(const f32x4*)(X + i);
    f32x4 b = *(const f32x4*)(X + i + 4);
    u16x8 o;
    o[0] = f2bf(a[0]); o[1] = f2bf(a[1]); o[2] = f2bf(a[2]); o[3] = f2bf(a[3]);
    o[4] = f2bf(b[0]); o[5] = f2bf(b[1]); o[6] = f2bf(b[2]); o[7] = f2bf(b[3]);
    *(u16x8*)(Xb + i) = o;
  } else if (bid < 8192) {
    int tt = bid - 4096;
    transp_f32(Wq, 4096, WT, 4096, tt & 63, tt >> 6, smem);
  } else if (bid < 9216) {
    int tt = bid - 8192;
    transp_f32(Wk, 1024, WT + (size_t)4096 * 4096, 4096, tt & 63, tt >> 6, smem);
  } else if (bid < 10240) {
    int tt = bid - 9216;
    transp_f32(Wv, 1024, WT + (size_t)5120 * 4096, 4096, tt & 63, tt >> 6, smem);
  } else {
    int i = (bid - 10240) * 256 + threadIdx.x;
    float v = (i < 4096) ? bq[i] : (i < 5120 ? bk[i - 4096] : bv[i - 5120]);
    bqkv[i] = v;
  }
}

// ---------------- QKV GEMM: 128x384 tile -> grid 16x16 = 256 WGs (100% CU coverage) ----------------
// 512 threads, 8 waves 2Mx4N, wave-out 64x96 (MRA=4, MRB=6, 24 MFMA/barrier). BK=32, ring-3
// (96KB), stage whole tile t+2 at top of t, counted vmcnt(4) (NL=4: A 1 unit + B 3 units of
// 128 rows), single barrier/tile, (cl>>1)&3 swizzle pair (verified 0-conflict).
// Epilogue: 2 passes of 64 rows via [64][392] LDS tile; 3 head-blocks (128 cols each, always
// uniformly Q, K, or V) scattered with the verified Q/Kf/Vf formulas.
__global__ __launch_bounds__(512, 2) void gemmqkv_k(const u16* __restrict__ A, const u16* __restrict__ Bt,
                                                    const float* __restrict__ bias,
                                                    const int* __restrict__ pos,
                                                    const float* __restrict__ cosT, const float* __restrict__ sinT,
                                                    u16* __restrict__ Q, u16* __restrict__ Kf,
                                                    u16* __restrict__ Vf, int K) {
  __shared__ __align__(16) u16 SM[49152];  // SA: 3x4096 u16, SB: 3x12288 u16 (96KB); epilogue reuses
  u16* SA = SM;
  u16* SB = SM + 12288;

  int tid = threadIdx.x;
  int w = tid >> 6, l = tid & 63;
  int cl = l & 15, g = l >> 4;
  int wr = w >> 2, wc = w & 3;

  int cpx = gridDim.x >> 3;  // XCD-bijective swizzle (256 % 8 == 0)
  int wg = (blockIdx.x & 7) * cpx + (blockIdx.x >> 3);
  int bm = wg & 15, bn = wg >> 4;  // nbm = 16, bn in [0,16)

  const u16* Ag = A + (size_t)(bm * 128) * K;
  const u16* Bg = Bt + (size_t)(bn * 384) * K;
  int srow = w * 16 + (l >> 2);                  // staging row within a 128-row unit
  int csrc = ((l & 3) ^ ((l >> 3) & 3)) * 8;     // inverse-swizzled global k-chunk
  int rdc = (g ^ ((cl >> 1) & 3)) << 3;          // forward swizzle on fragment ds_read

  f32x4 acc[4][6] = {};
  int NT = K >> 5;

  // unit 0 = A rows 0..128; units 1-3 = B rows (u-1)*128..+128. 512 thr x 16B = 8KB/unit.
  auto stage = [&](int slot, int tt, int u) {
    if (u == 0) {
      gload16(Ag + (size_t)srow * K + tt * 32 + csrc,
              (void*)(SA + slot * 4096 + w * 512));
    } else {
      int ub = u - 1;
      gload16(Bg + (size_t)(ub * 128 + srow) * K + tt * 32 + csrc,
              (void*)(SB + slot * 12288 + ub * 4096 + w * 512));
    }
  };

#pragma unroll
  for (int u = 0; u < 4; ++u) stage(0, 0, u);
#pragma unroll
  for (int u = 0; u < 4; ++u) stage(1, 1, u);

  for (int t = 0; t < NT; ++t) {
    asm volatile("s_waitcnt vmcnt(4)" ::: "memory");  // tile t done; t+1's 4 stay in flight
    __builtin_amdgcn_s_barrier();
    asm volatile("" ::: "memory");

    int slot = t % 3, ss = (t + 2) % 3;
    int ts = t + 2; if (ts >= NT) ts -= NT;  // dummy wrap keeps vmcnt accounting uniform
#pragma unroll
    for (int u = 0; u < 4; ++u) stage(ss, ts, u);

    const u16* sa = SA + slot * 4096;
    const u16* sb = SB + slot * 12288;
    bf16x8 af[4], bf[6];
#pragma unroll
    for (int mi = 0; mi < 4; ++mi)
      af[mi] = *(const bf16x8*)(sa + (wr * 64 + mi * 16 + cl) * 32 + rdc);
#pragma unroll
    for (int ni = 0; ni < 6; ++ni)
      bf[ni] = *(const bf16x8*)(sb + (wc * 96 + ni * 16 + cl) * 32 + rdc);
    __builtin_amdgcn_s_setprio(1);
#pragma unroll
    for (int mi = 0; mi < 4; ++mi)
#pragma unroll
      for (int ni = 0; ni < 6; ++ni)
        acc[mi][ni] = __builtin_amdgcn_mfma_f32_16x16x32_bf16(af[mi], bf[ni], acc[mi][ni], 0, 0, 0);
    __builtin_amdgcn_s_setprio(0);
  }

  asm volatile("s_waitcnt vmcnt(0)" ::: "memory");  // drain trailing dummy stages
  __syncthreads();

  // ---- epilogue: 2 passes of 64 rows via LDS tile [64][392] (stride 784B = 49*16B) ----
  u16 (*tileL)[392] = (u16 (*)[392])SM;
  const float qs = 0.08838834764831845f;  // 1/sqrt(128)
#pragma unroll
  for (int hp = 0; hp < 2; ++hp) {
    if (wr == hp) {
#pragma unroll
      for (int mi = 0; mi < 4; ++mi)
#pragma unroll
        for (int ni = 0; ni < 6; ++ni) {
          int col = wc * 96 + ni * 16 + cl;
          float bb = bias[bn * 384 + col];
#pragma unroll
          for (int r = 0; r < 4; ++r)
            tileL[mi * 16 + g * 4 + r][col] = f2bf(acc[mi][ni][r] + bb);
        }
    }
    __syncthreads();

    int s0 = bm * 128 + hp * 64;
#pragma unroll
    for (int hl = 0; hl < 3; ++hl) {
      int c0 = bn * 384 + hl * 128;  // 128-aligned global col base
      int hidx = c0 >> 7;            // [0,48): <32 Q, <40 K, else V
      if (hidx < 32) {
        // Q head hidx: RoPE + scale -> Q[h][s][128]
        int r = tid >> 3, u = tid & 7;
        int s = s0 + r;
        int ps = pos[s];
        const float* cb = cosT + (size_t)ps * 128;
        const float* sb = sinT + (size_t)ps * 128;
        u16* dst = Q + ((size_t)hidx * S_LEN + s) * HD;
        int d0 = u * 8;
        u16x8 xlo = *(const u16x8*)&tileL[r][hl * 128 + d0];
        u16x8 xhi = *(const u16x8*)&tileL[r][hl * 128 + d0 + 64];
        u16x8 lo, hi;
#pragma unroll
        for (int j = 0; j < 8; ++j) {
          int d = d0 + j;
          float x0 = bf2f(xlo[j]);
          float x1 = bf2f(xhi[j]);
          lo[j] = f2bf((x0 * cb[d] - x1 * sb[d]) * qs);
          hi[j] = f2bf((x1 * cb[d + 64] + x0 * sb[d + 64]) * qs);
        }
        *(u16x8*)(dst + d0) = lo;
        *(u16x8*)(dst + d0 + 64) = hi;
      } else if (hidx < 40) {
        // K head: RoPE -> Kf layout ((kh*64+t2)*8 + d/16)*512 + ((s&31)+32*((d>>3)&1))*8 + (d&7)
        int kh = hidx - 32;
        int r = tid >> 3, u = tid & 7;
        int s = s0 + r;
        int ps = pos[s];
        const float* cb = cosT + (size_t)ps * 128;
        const float* sb = sinT + (size_t)ps * 128;
        int t2 = s >> 5, cr = s & 31;
        int d0 = u * 8;
        u16x8 xlo = *(const u16x8*)&tileL[r][hl * 128 + d0];
        u16x8 xhi = *(const u16x8*)&tileL[r][hl * 128 + d0 + 64];
        u16x8 lo, hi;
#pragma unroll
        for (int j = 0; j < 8; ++j) {
          int d = d0 + j;
          float x0 = bf2f(xlo[j]);
          float x1 = bf2f(xhi[j]);
          lo[j] = f2bf(x0 * cb[d] - x1 * sb[d]);
          hi[j] = f2bf(x1 * cb[d + 64] + x0 * sb[d + 64]);
        }
        size_t base_lo = ((size_t)(kh * 64 + t2) * 8 + (d0 >> 4)) * 512 + (size_t)(cr + 32 * ((d0 >> 3) & 1)) * 8;
        *(u16x8*)(Kf + base_lo) = lo;
        int dh = d0 + 64;
        size_t base_hi = ((size_t)(kh * 64 + t2) * 8 + (dh >> 4)) * 512 + (size_t)(cr + 32 * ((dh >> 3) & 1)) * 8;
        *(u16x8*)(Kf + base_hi) = hi;
      } else {
        // V head -> Vf chunks (kh*512 + tglob*8 + dt*2 + sl)*512 + lv*8,
        //   elem j = V[t_local*32 + sl*16 + (lv>>5)*8 + j][dt*32 + (lv&31)]
        int kh = hidx - 40;
#pragma unroll
        for (int i = 0; i < 2; ++i) {
          int c = i * 512 + tid;  // [0,1024): 2 t_local x 8 (dt,sl) x 64 lanes
          int lv = c & 63, sl = (c >> 6) & 1, dt = (c >> 7) & 3, t_local = (c >> 9) & 1;
          int rl = t_local * 32 + sl * 16 + (lv >> 5) * 8;
          int colv = hl * 128 + dt * 32 + (lv & 31);
          u16x8 o;
#pragma unroll
          for (int j = 0; j < 8; ++j) o[j] = tileL[rl + j][colv];
          int tglob = bm * 4 + hp * 2 + t_local;
          size_t addr = ((size_t)(kh * 512 + tglob * 8 + dt * 2 + sl)) * 512 + (size_t)lv * 8;
          *(u16x8*)(Vf + addr) = o;
        }
      }
    }
    __syncthreads();
  }
}

// ---------------- Pipelined GEMM v4 (out-proj): r9-verified structure ----------------
template <int BM, int BN, int MINW, typename TOUT>
__global__ __launch_bounds__(256, MINW) void gemm4_k(const u16* __restrict__ A, const u16* __restrict__ Bt,
                                                     const float* __restrict__ bias, TOUT* __restrict__ C,
                                                     int M, int N, int K) {
  constexpr int WM = BM / 2, WN = BN / 2;
  constexpr int MRA = WM / 16, MRB = WN / 16;
  constexpr int NA = BM / 64, NB = BN / 64;
  constexpr int NL = NA + NB;
  __shared__ __align__(16) u16 SA[3 * BM * 32];
  __shared__ __align__(16) u16 SB[3 * BN * 32];

  int tid = threadIdx.x;
  int w = tid >> 6, l = tid & 63;
  int cl = l & 15, g = l >> 4;
  int wr = w >> 1, wc = w & 1;

  int cpx = gridDim.x >> 3;
  int wg = (blockIdx.x & 7) * cpx + (blockIdx.x >> 3);
  int nbm = M / BM;
  int bm = wg % nbm, bn = wg / nbm;

  const u16* Ag = A + (size_t)(bm * BM) * K;
  const u16* Bg = Bt + (size_t)(bn * BN) * K;
  int srow = w * 16 + (l >> 2);
  int csrc = ((l & 3) ^ ((l >> 3) & 3)) * 8;
  int rdc = (g ^ ((cl >> 1) & 3)) << 3;

  f32x4 acc[MRA][MRB] = {};
  int NT = K >> 5;

  auto stage = [&](int slot, int tt, int h) {
    if (h < NA) {
      gload16(Ag + (size_t)(h * 64 + srow) * K + tt * 32 + csrc,
              (void*)(SA + slot * (BM * 32) + (h * 64 + w * 16) * 32));
    } else {
      int hb = h - NA;
      gload16(Bg + (size_t)(hb * 64 + srow) * K + tt * 32 + csrc,
              (void*)(SB + slot * (BN * 32) + (hb * 64 + w * 16) * 32));
    }
  };

#pragma unroll
  for (int h = 0; h < NL; ++h) stage(0, 0, h);
#pragma unroll
  for (int h = 0; h < NL; ++h) stage(1, 1, h);

  for (int t = 0; t < NT; ++t) {
    if constexpr (NL == 5) asm volatile("s_waitcnt vmcnt(5)" ::: "memory");
    else if constexpr (NL == 4) asm volatile("s_waitcnt vmcnt(4)" ::: "memory");
    else asm volatile("s_waitcnt vmcnt(3)" ::: "memory");
    __builtin_amdgcn_s_barrier();
    asm volatile("" ::: "memory");

    int slot = t % 3, ss = (t + 2) % 3;
    int ts = t + 2; if (ts >= NT) ts -= NT;
#pragma unroll
    for (int h = 0; h < NL; ++h) stage(ss, ts, h);

    const u16* sa = SA + slot * (BM * 32);
    const u16* sb = SB + slot * (BN * 32);
    bf16x8 af[MRA], bf[MRB];
#pragma unroll
    for (int mi = 0; mi < MRA; ++mi)
      af[mi] = *(const bf16x8*)(sa + (wr * WM + mi * 16 + cl) * 32 + rdc);
#pragma unroll
    for (int ni = 0; ni < MRB; ++ni)
      bf[ni] = *(const bf16x8*)(sb + (wc * WN + ni * 16 + cl) * 32 + rdc);
    __builtin_amdgcn_s_setprio(1);
#pragma unroll
    for (int mi = 0; mi < MRA; ++mi)
#pragma unroll
      for (int ni = 0; ni < MRB; ++ni)
        acc[mi][ni] = __builtin_amdgcn_mfma_f32_16x16x32_bf16(af[mi], bf[ni], acc[mi][ni], 0, 0, 0);
    __builtin_amdgcn_s_setprio(0);
  }

  asm volatile("s_waitcnt vmcnt(0)" ::: "memory");

#pragma unroll
  for (int mi = 0; mi < MRA; ++mi) {
    int row0 = bm * BM + wr * WM + mi * 16 + g * 4;
#pragma unroll
    for (int ni = 0; ni < MRB; ++ni) {
      int col = bn * BN + wc * WN + ni * 16 + cl;
      float bb = bias[col];
      f32x4 a = acc[mi][ni];
#pragma unroll
      for (int r = 0; r < 4; ++r) {
        float v = a[r] + bb;
        if constexpr (sizeof(TOUT) == 2) C[(size_t)(row0 + r) * N + col] = f2bf(v);
        else C[(size_t)(row0 + r) * N + col] = v;
      }
    }
  }
}

// ---------------- flash attention (r11-best) + Wo^T transpose piggyback ----------------
// blocks [0,512): attn; blocks [512,4608): Wo^T transpose (backfills attn's imbalanced tail).
__global__ __launch_bounds__(256, 2) void attnwot_k(const u16* __restrict__ Q, const u16* __restrict__ Kf,
                                                    const u16* __restrict__ Vf, u16* __restrict__ O,
                                                    const float* __restrict__ Wo, u16* __restrict__ WT) {
  __shared__ __align__(16) char smem[17408];
  if (blockIdx.x >= 512) {
    int tt = blockIdx.x - 512;
    transp_f32(Wo, 4096, WT, 4096, tt & 63, tt >> 6, smem);
    return;
  }
  int l = threadIdx.x & 63, w = threadIdx.x >> 6;
  int col = l & 31, hi = l >> 5;
  int bid = blockIdx.x;
  int kh = bid & 7;
  int head = (bid >> 3) & 3;
  int qbp = bid >> 5;
  int qb = (qbp & 1) ? (15 - (qbp >> 1)) : (qbp >> 1);
  int h = kh * 4 + head;
  int q0 = qb * 128 + w * 32;

  bf16x8 qf[8];
  const u16* qbase = Q + ((size_t)h * S_LEN + q0 + col) * HD + hi * 8;
#pragma unroll
  for (int ks = 0; ks < 8; ++ks) qf[ks] = *(const bf16x8*)(qbase + ks * 16);

  f32x16 ot[4];
#pragma unroll
  for (int dt = 0; dt < 4; ++dt)
#pragma unroll
    for (int r = 0; r < 16; ++r) ot[dt][r] = 0.f;
  float m_r = -3.0e38f, l_r = 0.f;

  const u16* kf0 = Kf + (size_t)kh * 64 * 4096 + (size_t)l * 8;
  const u16* vf0 = Vf + (size_t)kh * 512 * 512 + (size_t)l * 8;

  int jstart = q0 >= WIN ? q0 - WIN : 0;
  bf16x8 kfr[8];
  {
    const u16* kb = kf0 + (size_t)(jstart >> 5) * 4096;
#pragma unroll
    for (int ks = 0; ks < 8; ++ks) kfr[ks] = *(const bf16x8*)(kb + ks * 512);
  }

  for (int j0 = jstart; j0 <= q0; j0 += 32) {
    int t = j0 >> 5;
    f32x16 sA = {}, sB = {};
#pragma unroll
    for (int ks = 0; ks < 4; ++ks)
      sA = __builtin_amdgcn_mfma_f32_32x32x16_bf16(kfr[ks], qf[ks], sA, 0, 0, 0);
#pragma unroll
    for (int ks = 4; ks < 8; ++ks)
      sB = __builtin_amdgcn_mfma_f32_32x32x16_bf16(kfr[ks], qf[ks], sB, 0, 0, 0);
    int tn = (j0 + 32 <= q0) ? (t + 1) : t;
    const u16* kbn = kf0 + (size_t)tn * 4096;
    bf16x8 kfn[8];
#pragma unroll
    for (int ks = 0; ks < 8; ++ks) kfn[ks] = *(const bf16x8*)(kbn + ks * 512);
    const u16* vb = vf0 + (size_t)t * 4096;
    bf16x8 vfr[8];
#pragma unroll
    for (int c = 0; c < 8; ++c) vfr[c] = *(const bf16x8*)(vb + c * 512);

    f32x16 s = sA + sB;

    if (j0 + 31 > q0 || j0 < q0 - 992) {
      int q = q0 + col;
#pragma unroll
      for (int r = 0; r < 16; ++r) {
        int kv = j0 + (r & 3) + 8 * (r >> 2) + 4 * hi;
        if (kv > q || kv <= q - WIN) s[r] = -3.0e38f;
      }
    }
    float vm = fmaxf(fmaxf(fmaxf(s[0], s[1]), fmaxf(s[2], s[3])),
                     fmaxf(fmaxf(s[4], s[5]), fmaxf(s[6], s[7])));
    vm = fmaxf(vm, fmaxf(fmaxf(fmaxf(s[8], s[9]), fmaxf(s[10], s[11])),
                         fmaxf(fmaxf(s[12], s[13]), fmaxf(s[14], s[15]))));
    vm = fmaxf(vm, __shfl_xor(vm, 32));
    float mnew = fmaxf(m_r, vm);
    float sc = __expf(m_r - mnew);
    m_r = mnew;
    float rs = 0.f;
#pragma unroll
    for (int r = 0; r < 16; ++r) {
      float pv = __expf(s[r] - mnew);
      s[r] = pv;
      rs += pv;
    }
    rs += __shfl_xor(rs, 32);
    l_r = l_r * sc + rs;
#pragma unroll
    for (int dt = 0; dt < 4; ++dt)
#pragma unroll
      for (int r = 0; r < 16; ++r) ot[dt][r] *= sc;

    bf16x8 pb[2];
#pragma unroll
    for (int sl = 0; sl < 2; ++sl) {
      int b = sl * 8;
      unsigned int a0 = cvtpk_bf16(s[b + 0], s[b + 1]);
      unsigned int c0 = cvtpk_bf16(s[b + 4], s[b + 5]);
      asm("v_permlane32_swap_b32 %0, %1" : "+v"(a0), "+v"(c0));
      unsigned int a1 = cvtpk_bf16(s[b + 2], s[b + 3]);
      unsigned int c1 = cvtpk_bf16(s[b + 6], s[b + 7]);
      asm("v_permlane32_swap_b32 %0, %1" : "+v"(a1), "+v"(c1));
      u32x4 pv = {a0, a1, c0, c1};
      pb[sl] = __builtin_bit_cast(bf16x8, pv);
    }
#pragma unroll
    for (int dt = 0; dt < 4; ++dt) {
      ot[dt] = __builtin_amdgcn_mfma_f32_32x32x16_bf16(vfr[dt * 2 + 0], pb[0], ot[dt], 0, 0, 0);
      ot[dt] = __builtin_amdgcn_mfma_f32_32x32x16_bf16(vfr[dt * 2 + 1], pb[1], ot[dt], 0, 0, 0);
    }
#pragma unroll
    for (int ks = 0; ks < 8; ++ks) kfr[ks] = kfn[ks];
  }

  float inv = 1.0f / l_r;
#pragma unroll
  for (int dt = 0; dt < 4; ++dt) {
#pragma unroll
    for (int g2 = 0; g2 < 4; ++g2) {
      u16x4 o;
#pragma unroll
      for (int i = 0; i < 4; ++i) o[i] = f2bf(ot[dt][g2 * 4 + i] * inv);
      *(u16x4*)(O + (size_t)(q0 + col) * HIDDEN + h * HD + dt * 32 + g2 * 8 + hi * 4) = o;
    }
  }
}

extern "C" void kernel_launch(void* const* d_in, const int* in_sizes, int n_in,
                              void* d_out, int out_size, void* d_ws, size_t ws_size,
                              hipStream_t stream) {
  const float* X = (const float*)d_in[0];
  const int* pos = (const int*)d_in[2];
  const float* cosT = (const float*)d_in[3];
  const float* sinT = (const float*)d_in[4];
  const float* Wq = (const float*)d_in[5];
  const float* bq = (const float*)d_in[6];
  const float* Wk = (const float*)d_in[7];
  const float* bk = (const float*)d_in[8];
  const float* Wv = (const float*)d_in[9];
  const float* bv = (const float*)d_in[10];
  const float* Wo = (const float*)d_in[11];
  const float* bo = (const float*)d_in[12];
  float* out = (float*)d_out;

  const size_t MB = 1ull << 20;
  char* ws = (char*)d_ws;
  u16* WT = (u16*)ws;                     // 48MB: Wqkv^T bf16; Wo^T overwrites after QKV GEMM
  u16* Xb = (u16*)(ws + 48 * MB);         // 16MB: X bf16 (dead after QKV GEMM); attnO reuses
  u16* attnO = Xb;
  u16* Qs = (u16*)(ws + 64 * MB);         // 16MB: Q [32][2048][128]
  u16* Kfr = (u16*)(ws + 88 * MB);        // 4MB: K fragment-packed
  u16* Vfr = (u16*)(ws + 92 * MB);        // 4MB: V fragment-packed
  float* bqkv = (float*)(ws + 96 * MB);   // 24KB

  // prep: conv + Wq/Wk/Wv transposes + bias concat
  prep_k<<<10264, 256, 0, stream>>>(X, Wq, Wk, Wv, bq, bk, bv, Xb, WT, bqkv);

  // QKV GEMM (128x384 tiles, 256 WGs = 100% CU coverage) + fused RoPE/scatter epilogue
  gemmqkv_k<<<256, 512, 0, stream>>>(Xb, WT, bqkv, pos, cosT, sinT, Qs, Kfr, Vfr, 4096);

  // attn (512 blocks) + Wo^T transpose (4096 blocks, overlaps attn tail)
  attnwot_k<<<4608, 256, 0, stream>>>(Qs, Kfr, Vfr, attnO, Wo, WT);

  // out-proj: 128x128 tiles, 512 WGs
  gemm4_k<128, 128, 3, float><<<512, 256, 0, stream>>>(attnO, WT, bo, out, 2048, 4096, 4096);
}